// Round 18
// baseline (341.599 us; speedup 1.0000x reference)
//
#include <hip/hip_runtime.h>
#include <hip/hip_fp16.h>

#define D 64
#define TB 256

// Bucketing: users 1024 nodes/bucket, artists 256 nodes/bucket.
#define BSHIFT_U 10
#define BSHIFT_A 8
#define SHARDS 8
#define SCAP   1536    // per-shard per-bucket part capacity (mean 1276, 7.3 sigma)
#define CAP    (SHARDS * SCAP)   // 12288 per-bucket part capacity
#define CAPC_U 16384   // csr user-bucket capacity (2 sub-regions of 8192)
#define CAPC_A 12288   // csr artist-bucket capacity (2 sub-regions of 6144)
#define TSHIFT 14      // source-tile shift (16K ids/tile) for sorted CSR
#define PCHUNK 2048    // partition LDS sort chunk
#define EPT    (PCHUNK / TB)   // 8 edges per thread, register-staged

typedef _Float16 half8 __attribute__((ext_vector_type(8)));
typedef float float8 __attribute__((ext_vector_type(8)));
typedef float f32x4 __attribute__((ext_vector_type(4)));

__device__ __forceinline__ float8 h8_to_f8(half8 h) {
    return __builtin_convertvector(h, float8);
}
template <typename T>
__device__ __forceinline__ T ntl(const T* p) { return __builtin_nontemporal_load(p); }
template <typename T>
__device__ __forceinline__ void nts(T* p, T v) { __builtin_nontemporal_store(v, p); }

// Register-staged LDS counting-sort partition with x8-sharded bucket cursors
// and wave-shuffle scan. Trailing blocks do the fp32->fp16 conversion.
__global__ __launch_bounds__(TB) void partition_cvt_kernel(const int* __restrict__ art,
                                                           const int* __restrict__ usr, int E,
                                                           int* __restrict__ bcur_u,
                                                           int* __restrict__ bcur_a,
                                                           unsigned* __restrict__ part_u,
                                                           unsigned* __restrict__ part_a,
                                                           int NBu, int NBa,
                                                           const f32x4* __restrict__ cvt_in,
                                                           half8* __restrict__ cvt_out,
                                                           int n8, int nPartBlocks) {
    __shared__ unsigned sorted[PCHUNK];   // 8KB
    __shared__ int cnt[256];
    __shared__ int seg[256];
    __shared__ int gbase[256];
    __shared__ int swsum[4];
    const int tid = threadIdx.x;
    if ((int)blockIdx.x >= nPartBlocks) {
        int i = (blockIdx.x - nPartBlocks) * TB + tid;
        int stride = (gridDim.x - nPartBlocks) * TB;
        for (; i < n8; i += stride) {
            f32x4 a = cvt_in[i * 2 + 0];
            f32x4 b = cvt_in[i * 2 + 1];
            half8 h;
            h[0] = (_Float16)a[0]; h[1] = (_Float16)a[1]; h[2] = (_Float16)a[2]; h[3] = (_Float16)a[3];
            h[4] = (_Float16)b[0]; h[5] = (_Float16)b[1]; h[6] = (_Float16)b[2]; h[7] = (_Float16)b[3];
            cvt_out[i] = h;
        }
        return;
    }
    const int dir = blockIdx.x & 1;
    const int cidx = blockIdx.x >> 1;
    const int shard = cidx & (SHARDS - 1);
    const int c0 = cidx * PCHUNK;
    if (c0 >= E) return;
    const int m = min(PCHUNK, E - c0);
    const int NB = dir ? NBa : NBu;
    const int BSH = dir ? BSHIFT_A : BSHIFT_U;
    int* bcur = dir ? bcur_a : bcur_u;  // [NB][SHARDS]
    unsigned* part = dir ? part_a : part_u;
    const unsigned mask = (1u << BSH) - 1u;

    for (int i = tid; i < NB; i += TB) cnt[i] = 0;
    unsigned rec[EPT];
    int bk[EPT], rk[EPT];
    for (int k = 0; k < EPT; ++k) {
        int i = tid + k * TB;
        if (i < m) {
            int a = art[c0 + i], u = usr[c0 + i];
            int kk = dir ? a : u;   // dst id
            int ss = dir ? u : a;   // src id
            rec[k] = ((unsigned)ss << BSH) | ((unsigned)kk & mask);
            bk[k] = kk >> BSH;
        } else bk[k] = -1;
    }
    __syncthreads();
    for (int k = 0; k < EPT; ++k)
        if (bk[k] >= 0) rk[k] = atomicAdd(&cnt[bk[k]], 1);
    __syncthreads();
    int v = (tid < NB) ? cnt[tid] : 0;
    const int lane = tid & 63, wv = tid >> 6;
    int x = v;
    for (int o = 1; o < 64; o <<= 1) {
        int t = __shfl_up(x, o);
        if (lane >= o) x += t;
    }
    if (lane == 63) swsum[wv] = x;
    __syncthreads();
    int woff = 0;
    for (int k = 0; k < wv; ++k) woff += swsum[k];
    if (tid < NB) {
        seg[tid] = x + woff - v;
        if (v) gbase[tid] = tid * CAP + shard * SCAP +
                            atomicAdd(&bcur[tid * SHARDS + shard], v);
    }
    __syncthreads();
    for (int k = 0; k < EPT; ++k)
        if (bk[k] >= 0) sorted[seg[bk[k]] + rk[k]] = rec[k];
    __syncthreads();
    for (int b = wv; b < NB; b += TB / 64) {
        int s = seg[b];
        int send = (b + 1 < NB) ? seg[b + 1] : m;
        if (send <= s) continue;
        unsigned* dst = part + (size_t)gbase[b];
        for (int i = s + lane; i < send; i += 64) dst[i - s] = sorted[i];
    }
}

// Sub-bucket source-tile-sorted CSR build: TWO blocks per bucket, each owns
// NPB_SUB local nodes (filter by local-id range). 2048 LDS bins, wave-shuffle
// scan, x4-padded node segments (dummy id 0), per-(bucket,sub) csr region.
template <int NPB_SUB, int NB, int BSHIFT, int SUBBITS, typename IT>
__device__ __forceinline__ void local_csr_body(const unsigned* __restrict__ part,
                                               const int* __restrict__ shard_cnt, // [SHARDS]
                                               int ebeg_p, int ebeg_c, int n0, int sub,
                                               int2* __restrict__ rowdeg,
                                               IT* __restrict__ csr, int N,
                                               int* cnt, int* swsum) {
    const int tid = threadIdx.x;
    const int NBINS = NPB_SUB * NB;      // 2048 for both configs
    const unsigned maskL = (1u << BSHIFT) - 1u;
    const unsigned maskS = (unsigned)(NPB_SUB - 1);
    int cs[SHARDS];
    for (int s = 0; s < SHARDS; ++s) cs[s] = shard_cnt[s];
    for (int i = tid; i < NBINS; i += TB) cnt[i] = 0;
    __syncthreads();
    for (int s = 0; s < SHARDS; ++s) {
        const int base = ebeg_p + s * SCAP;
        const int endv = base + cs[s];
        for (int e = base + tid; e < endv; e += TB) {
            unsigned r = part[e];
            int l = (int)(r & maskL);
            if ((l >> SUBBITS) == sub) {
                int bin = (int)(l & maskS) * NB + (int)((r >> BSHIFT) >> TSHIFT);
                atomicAdd(&cnt[bin], 1);
            }
        }
    }
    __syncthreads();
    constexpr int NPT = (NPB_SUB + TB - 1) / TB;   // 2 (user) / 1 (artist)
    int dj[NPT], pdj[NPT], nsj[NPT];
    int local = 0;
    for (int j = 0; j < NPT; ++j) {
        int nl = tid * NPT + j;
        int d = 0;
        if (nl < NPB_SUB)
            for (int k = 0; k < NB; ++k) d += cnt[nl * NB + k];
        dj[j] = d;
        pdj[j] = (d + 3) & ~3;
        local += pdj[j];
    }
    // wave-shuffle exclusive scan of per-thread padded totals
    const int lane = tid & 63, wvi = tid >> 6;
    int x = local;
    for (int o = 1; o < 64; o <<= 1) {
        int t = __shfl_up(x, o);
        if (lane >= o) x += t;
    }
    if (lane == 63) swsum[wvi] = x;
    __syncthreads();
    int woff = 0;
    for (int k = 0; k < wvi; ++k) woff += swsum[k];
    int run = x + woff - local;
    for (int j = 0; j < NPT; ++j) {
        int nl = tid * NPT + j;
        nsj[j] = run;
        if (nl < NPB_SUB) {
            int c = run;
            for (int k = 0; k < NB; ++k) {
                int idx = nl * NB + k;
                int v = cnt[idx];
                cnt[idx] = c;            // per-bin fill cursor
                c += v;
            }
            int n = n0 + nl;
            if (n < N) rowdeg[n] = make_int2(ebeg_c + run, dj[j]);
        }
        run += pdj[j];
    }
    __syncthreads();
    for (int s = 0; s < SHARDS; ++s) {
        const int base = ebeg_p + s * SCAP;
        const int endv = base + cs[s];
        for (int e = base + tid; e < endv; e += TB) {
            unsigned r = part[e];
            int l = (int)(r & maskL);
            if ((l >> SUBBITS) == sub) {
                int bin = (int)(l & maskS) * NB + (int)((r >> BSHIFT) >> TSHIFT);
                int pos = atomicAdd(&cnt[bin], 1);
                csr[ebeg_c + pos] = (IT)(r >> BSHIFT);
            }
        }
    }
    // pad fill: dummy id 0 in [d, pd) of each node segment
    for (int j = 0; j < NPT; ++j)
        for (int k = dj[j]; k < pdj[j]; ++k) csr[ebeg_c + nsj[j] + k] = (IT)0;
}

// Grid: [0, 2*NBu) user sub-buckets, [2*NBu, 2*NBu+2*NBa) artist sub-buckets.
__global__ __launch_bounds__(TB) void local_csr_both_kernel(const unsigned* __restrict__ part_u,
                                                            const unsigned* __restrict__ part_a,
                                                            const int* __restrict__ bcur_u,
                                                            const int* __restrict__ bcur_a,
                                                            int2* __restrict__ rowdeg_u,
                                                            int2* __restrict__ rowdeg_a,
                                                            unsigned short* __restrict__ csr_u,
                                                            int* __restrict__ csr_a,
                                                            int NU, int NA, int NBu) {
    __shared__ int cnt[2048];
    __shared__ int swsum[4];
    const int b = blockIdx.x;
    if (b < 2 * NBu) {
        const int bk = b >> 1, sub = b & 1;
        local_csr_body<512, 4, BSHIFT_U, 9>(part_u, bcur_u + bk * SHARDS, bk * CAP,
                                            b * (CAPC_U / 2),
                                            (bk << BSHIFT_U) + sub * 512, sub,
                                            rowdeg_u, csr_u, NU, cnt, swsum);
    } else {
        const int bb = b - 2 * NBu;
        const int bk = bb >> 1, sub = bb & 1;
        local_csr_body<128, 16, BSHIFT_A, 7>(part_a, bcur_a + bk * SHARDS, bk * CAP,
                                             bb * (CAPC_A / 2),
                                             (bk << BSHIFT_A) + sub * 128, sub,
                                             rowdeg_a, csr_a, NA, cnt, swsum);
    }
}

// L-lane group per (node, row-slice); L=4 for BOTH sides now (2x groups/wave,
// 2x outstanding loads - latency-bound gathers). Uniform 4-wide edge loop
// (x4-padded CSR, dummy id 0) + 8-wide unroll; correction sum -= (pd-deg)*r0.
template <int L, typename IT>
__global__ __launch_bounds__(TB) void gather_mean_kernel(const half8* __restrict__ src,
                                                         const IT* __restrict__ csr,
                                                         const int2* __restrict__ rowdeg,
                                                         half8* __restrict__ x_out,
                                                         f32x4* __restrict__ final_acc,
                                                         const f32x4* __restrict__ init_src,
                                                         const f32x4* __restrict__ fin_in0,
                                                         const half8* __restrict__ fin_x1,
                                                         const half8* __restrict__ fin_x2,
                                                         f32x4* __restrict__ fin_out,
                                                         int N, float scale) {
    constexpr int SPLIT = 8 / L;        // row-slices per row
    const int lane = threadIdx.x & (L - 1);
    const int g = (blockIdx.x * blockDim.x + threadIdx.x) / L;
    const int ngroups = (gridDim.x * blockDim.x) / L;
    const int sub = g % SPLIT;
    const int cb = sub * L + lane;       // half8-chunk index within row, 0..7
    const int n0 = g / SPLIT;
    const int nstride = ngroups / SPLIT;
    const float8 r0 = h8_to_f8(src[cb]);   // row 0 slice (dummy target), hoisted
    for (int n = n0; n < N; n += nstride) {
        const int2 rd = rowdeg[n];
        const int beg = rd.x;
        const int dg = rd.y;
        const int pd = (dg + 3) & ~3;
        const int end = beg + pd;
        float8 a0 = 0.f, a1 = 0.f, a2 = 0.f, a3 = 0.f;
        int e = beg;
        for (; e + 8 <= end; e += 8) {
            const int s0 = (int)csr[e + 0];
            const int s1 = (int)csr[e + 1];
            const int s2 = (int)csr[e + 2];
            const int s3 = (int)csr[e + 3];
            const int s4 = (int)csr[e + 4];
            const int s5 = (int)csr[e + 5];
            const int s6 = (int)csr[e + 6];
            const int s7 = (int)csr[e + 7];
            const half8 v0 = src[s0 * 8 + cb];
            const half8 v1 = src[s1 * 8 + cb];
            const half8 v2 = src[s2 * 8 + cb];
            const half8 v3 = src[s3 * 8 + cb];
            const half8 v4 = src[s4 * 8 + cb];
            const half8 v5 = src[s5 * 8 + cb];
            const half8 v6 = src[s6 * 8 + cb];
            const half8 v7 = src[s7 * 8 + cb];
            a0 += h8_to_f8(v0);
            a1 += h8_to_f8(v1);
            a2 += h8_to_f8(v2);
            a3 += h8_to_f8(v3);
            a0 += h8_to_f8(v4);
            a1 += h8_to_f8(v5);
            a2 += h8_to_f8(v6);
            a3 += h8_to_f8(v7);
        }
        if (e < end) {   // exactly one 4-wide iteration (pd % 4 == 0)
            const int s0 = (int)csr[e + 0];
            const int s1 = (int)csr[e + 1];
            const int s2 = (int)csr[e + 2];
            const int s3 = (int)csr[e + 3];
            a0 += h8_to_f8(src[s0 * 8 + cb]);
            a1 += h8_to_f8(src[s1 * 8 + cb]);
            a2 += h8_to_f8(src[s2 * 8 + cb]);
            a3 += h8_to_f8(src[s3 * 8 + cb]);
        }
        float8 s = (a0 + a1) + (a2 + a3);
        s -= (float)(pd - dg) * r0;
        const float inv = 1.f / (float)(dg > 0 ? dg : 1);
        float8 x = s * inv;
        const int o8 = n * 8 + cb;
        if (x_out != nullptr) {
            half8 h;
            for (int k = 0; k < 8; ++k) h[k] = (_Float16)x[k];
            x_out[o8] = h;
        }
        const int fo = n * (D / 4) + cb * 2;
        if (fin_out != nullptr) {
            float8 t = h8_to_f8(ntl(&fin_x1[o8])) + h8_to_f8(ntl(&fin_x2[o8])) + x;
            f32x4 f0 = ntl(&fin_in0[fo + 0]);
            f32x4 f1 = ntl(&fin_in0[fo + 1]);
            f32x4 t0 = {t[0], t[1], t[2], t[3]};
            f32x4 t1 = {t[4], t[5], t[6], t[7]};
            nts(&fin_out[fo + 0], (f0 + t0) * scale);
            nts(&fin_out[fo + 1], (f1 + t1) * scale);
        }
        if (final_acc != nullptr) {
            f32x4 f0, f1;
            if (init_src != nullptr) {
                f0 = init_src[fo + 0] * scale;
                f1 = init_src[fo + 1] * scale;
            } else {
                f0 = final_acc[fo + 0];
                f1 = final_acc[fo + 1];
            }
            f32x4 x0 = {x[0], x[1], x[2], x[3]};
            f32x4 x1 = {x[4], x[5], x[6], x[7]};
            final_acc[fo + 0] = f0 + x0 * scale;
            final_acc[fo + 1] = f1 + x1 * scale;
        }
    }
}

extern "C" void kernel_launch(void* const* d_in, const int* in_sizes, int n_in,
                              void* d_out, int out_size, void* d_ws, size_t ws_size,
                              hipStream_t stream) {
    const float* x_users   = (const float*)d_in[0];
    const float* x_artists = (const float*)d_in[1];
    const int*   a2u       = (const int*)d_in[2];  // row0: artist(src), row1: user(dst)

    const int NU = in_sizes[0] / D;
    const int NA = in_sizes[1] / D;
    const int E  = in_sizes[2] / 2;
    const int* art = a2u;
    const int* usr = a2u + E;

    const float scale = 0.25f;   // 1/(NUM_LAYERS+1)

    const int NBu = (NU + (1 << BSHIFT_U) - 1) >> BSHIFT_U;  // 196
    const int NBa = (NA + (1 << BSHIFT_A) - 1) >> BSHIFT_A;  // 196

    // ---- workspace layout (256B aligned) ----
    char* w = (char*)d_ws;
    size_t off = 0;
    auto alloc = [&](size_t bytes) -> char* {
        char* p = w + off;
        off += (bytes + 255) & ~(size_t)255;
        return p;
    };
    int2* rowdeg_u = (int2*)alloc((size_t)NU * 8);
    int2* rowdeg_a = (int2*)alloc((size_t)NA * 8);
    int* bcur      = (int*)alloc((size_t)(NBu + NBa) * SHARDS * 4);
    int* bcur_u    = bcur;                        // [NBu][SHARDS]
    int* bcur_a    = bcur + NBu * SHARDS;         // [NBa][SHARDS]
    unsigned short* csr_u = (unsigned short*)alloc((size_t)NBu * CAPC_U * 2);
    int* csr_a     = (int*)alloc((size_t)NBa * CAPC_A * 4);
    half8* xa_in   = (half8*)alloc((size_t)NA * D * 2);   // fp16 copy of x_artists
    unsigned* part_u = (unsigned*)alloc((size_t)NBu * CAP * 4);
    unsigned* part_a = (unsigned*)alloc((size_t)NBa * CAP * 4);

    const size_t XU = (size_t)NU * D * 2;                 // 25.6 MB
    const size_t XA = (size_t)NA * D * 2;                 // 6.4 MB
    const size_t XUa = (XU + 255) & ~(size_t)255;
    const size_t XAa = (XA + 255) & ~(size_t)255;

    const bool modeA = (off + 3 * XUa) <= ws_size;

    half8* x_u1 = (half8*)alloc(XU);
    half8* x_u2 = modeA ? (half8*)alloc(XU) : x_u1;
    half8* x_u3 = modeA ? (half8*)alloc(XU) : x_u1;
    // x_a buffers overlay the (dead-after-build) part region (19.2MB >= 12.8MB)
    char* part_base = (char*)part_u;
    half8* x_a1 = (half8*)(part_base);
    half8* x_a2 = modeA ? (half8*)(part_base + XAa) : x_a1;

    float* out_u = (float*)d_out;
    float* out_a = out_u + (size_t)NU * D;

    // ---- sorted CSR build (register-staged partition + fused cvt) ----
    hipMemsetAsync(bcur, 0, (size_t)(NBu + NBa) * SHARDS * 4, stream);
    const int nchunks = (E + PCHUNK - 1) / PCHUNK;
    const int nPart = 2 * nchunks;
    partition_cvt_kernel<<<nPart + 128, TB, 0, stream>>>(art, usr, E, bcur_u, bcur_a,
                                                         part_u, part_a, NBu, NBa,
                                                         (const f32x4*)x_artists, xa_in,
                                                         NA * D / 8, nPart);
    local_csr_both_kernel<<<2 * (NBu + NBa), TB, 0, stream>>>(part_u, part_a, bcur_u, bcur_a,
                                                              rowdeg_u, rowdeg_a,
                                                              csr_u, csr_a, NU, NA, NBu);

    // ---- 3 propagation layers ----
    half8* xu_buf[3] = {x_u1, x_u2, x_u3};
    half8* xa_buf[2] = {x_a1, x_a2};           // l=2 artist writes out only (Mode A)
    const half8* srcA = xa_in;
    for (int l = 0; l < 3; ++l) {
        const bool last = (l == 2);
        // users <- artists : 4-lane groups, uint16 csr
        gather_mean_kernel<4, unsigned short><<<6400, TB, 0, stream>>>(
            srcA, csr_u, rowdeg_u, xu_buf[l],
            modeA ? nullptr : (f32x4*)out_u,
            (!modeA && l == 0) ? (const f32x4*)x_users : nullptr,
            (modeA && last) ? (const f32x4*)x_users : nullptr,
            (modeA && last) ? x_u1 : nullptr,
            (modeA && last) ? x_u2 : nullptr,
            (modeA && last) ? (f32x4*)out_u : nullptr,
            NU, scale);
        // artists <- users : 4-lane groups, int csr
        gather_mean_kernel<4, int><<<1600, TB, 0, stream>>>(
            xu_buf[l], csr_a, rowdeg_a,
            (modeA && last) ? nullptr : (modeA ? xa_buf[l] : x_a1),
            modeA ? nullptr : (f32x4*)out_a,
            (!modeA && l == 0) ? (const f32x4*)x_artists : nullptr,
            (modeA && last) ? (const f32x4*)x_artists : nullptr,
            (modeA && last) ? x_a1 : nullptr,
            (modeA && last) ? x_a2 : nullptr,
            (modeA && last) ? (f32x4*)out_a : nullptr,
            NA, scale);
        srcA = modeA ? xa_buf[l < 2 ? l : 0] : x_a1;
    }
}

// Round 19
// 332.694 us; speedup vs baseline: 1.0268x; 1.0268x over previous
//
#include <hip/hip_runtime.h>
#include <hip/hip_fp16.h>

#define D 64
#define TB 256

// Bucketing: users 1024 nodes/bucket, artists 256 nodes/bucket.
#define BSHIFT_U 10
#define BSHIFT_A 8
#define SHARDS 8
#define SCAP   1536    // per-shard per-bucket part capacity (mean 1276, 7.3 sigma)
#define CAP    (SHARDS * SCAP)   // 12288 per-bucket part capacity
#define CAPC_U 16384   // csr user-bucket capacity (x4-padded segments; mean ~11740)
#define CAPC_A 12288   // csr artist-bucket capacity (x4-padded; mean ~10590)
#define TSHIFT 14      // source-tile shift (16K ids/tile) for sorted CSR
#define PCHUNK 2048    // partition LDS sort chunk (16KB LDS -> 8 blocks/CU)

typedef _Float16 half8 __attribute__((ext_vector_type(8)));
typedef float float8 __attribute__((ext_vector_type(8)));
typedef float f32x4 __attribute__((ext_vector_type(4)));

__device__ __forceinline__ float8 h8_to_f8(half8 h) {
    return __builtin_convertvector(h, float8);
}
template <typename T>
__device__ __forceinline__ T ntl(const T* p) { return __builtin_nontemporal_load(p); }
template <typename T>
__device__ __forceinline__ void nts(T* p, T v) { __builtin_nontemporal_store(v, p); }

// Slim LDS counting-sort partition with x8-sharded bucket cursors, PLUS
// fused fp32->fp16 conversion in trailing blocks (removes a serial dispatch).
struct PartShared {
    unsigned sorted[PCHUNK];      // 8KB
    unsigned short loc[PCHUNK];   // 4KB
    int cnt[256];
    int gbase[256];               // absolute part index for this block's run
    int seg[256];
    int scanbuf[TB];
};

__global__ __launch_bounds__(TB) void partition_cvt_kernel(const int* __restrict__ art,
                                                           const int* __restrict__ usr, int E,
                                                           int* __restrict__ bcur_u,
                                                           int* __restrict__ bcur_a,
                                                           unsigned* __restrict__ part_u,
                                                           unsigned* __restrict__ part_a,
                                                           int NBu, int NBa,
                                                           const f32x4* __restrict__ cvt_in,
                                                           half8* __restrict__ cvt_out,
                                                           int n8, int nPartBlocks) {
    __shared__ PartShared sh;
    const int tid = threadIdx.x;
    if ((int)blockIdx.x >= nPartBlocks) {
        // ---- cvt tail-blocks: fp32 -> fp16 row conversion ----
        int i = (blockIdx.x - nPartBlocks) * TB + tid;
        int stride = (gridDim.x - nPartBlocks) * TB;
        for (; i < n8; i += stride) {
            f32x4 a = cvt_in[i * 2 + 0];
            f32x4 b = cvt_in[i * 2 + 1];
            half8 h;
            h[0] = (_Float16)a[0]; h[1] = (_Float16)a[1]; h[2] = (_Float16)a[2]; h[3] = (_Float16)a[3];
            h[4] = (_Float16)b[0]; h[5] = (_Float16)b[1]; h[6] = (_Float16)b[2]; h[7] = (_Float16)b[3];
            cvt_out[i] = h;
        }
        return;
    }
    const int dir = blockIdx.x & 1;
    const int cidx = blockIdx.x >> 1;
    const int shard = cidx & (SHARDS - 1);
    const int c0 = cidx * PCHUNK;
    if (c0 >= E) return;
    const int m = min(PCHUNK, E - c0);
    const int NB = dir ? NBa : NBu;
    const int BSH = dir ? BSHIFT_A : BSHIFT_U;
    const int* key = dir ? art : usr;   // destination id array for this direction
    int* bcur = dir ? bcur_a : bcur_u;  // [NB][SHARDS]
    unsigned* part = dir ? part_a : part_u;

    for (int i = tid; i < NB; i += TB) sh.cnt[i] = 0;
    __syncthreads();
    // phase 1: per-bucket count + per-record rank
    for (int i = tid; i < m; i += TB) {
        int b = key[c0 + i] >> BSH;
        sh.loc[i] = (unsigned short)atomicAdd(&sh.cnt[b], 1);
    }
    __syncthreads();
    // phase 2: scan + sharded exact global claim
    int v = (tid < NB) ? sh.cnt[tid] : 0;
    sh.scanbuf[tid] = v;
    __syncthreads();
    for (int off = 1; off < TB; off <<= 1) {
        int t = (tid >= off) ? sh.scanbuf[tid - off] : 0;
        __syncthreads();
        if (tid >= off) sh.scanbuf[tid] += t;
        __syncthreads();
    }
    if (tid < NB) {
        sh.seg[tid] = sh.scanbuf[tid] - v;
        if (v) {
            int old = atomicAdd(&bcur[tid * SHARDS + shard], v);
            sh.gbase[tid] = tid * CAP + shard * SCAP + old;
        }
    }
    __syncthreads();
    // phase 3: rebuild records (2nd edge read, L2-hot), scatter into LDS
    const unsigned mask = (1u << BSH) - 1u;
    for (int i = tid; i < m; i += TB) {
        int a = art[c0 + i], u = usr[c0 + i];
        int k = dir ? a : u;   // dst id
        int s = dir ? u : a;   // src id
        int b = k >> BSH;
        sh.sorted[sh.seg[b] + sh.loc[i]] = ((unsigned)s << BSH) | ((unsigned)k & mask);
    }
    __syncthreads();
    // phase 4: coalesced copy-out, wave per bucket round-robin
    const int wid = tid >> 6;
    const int lane = tid & 63;
    for (int b = wid; b < NB; b += TB / 64) {
        int s = sh.seg[b];
        int send = (b + 1 < NB) ? sh.seg[b + 1] : m;
        if (send <= s) continue;
        unsigned* dst = part + (size_t)sh.gbase[b];
        for (int i = s + lane; i < send; i += 64) dst[i - s] = sh.sorted[i];
    }
}

// Source-tile-sorted per-bucket CSR build with x4-padded node segments.
// Reads the bucket's 8 shard sub-segments; bin = local*NB + (src >> TSHIFT);
// dummies (id 0) pad each node's segment to a multiple of 4.
// IT = csr element type (ushort for user buckets: artist ids < 65536).
template <int NPB, int NB, int BSHIFT, typename IT>
__device__ __forceinline__ void local_csr_body(const unsigned* __restrict__ part,
                                               const int* __restrict__ shard_cnt, // [SHARDS]
                                               int ebeg_p, int ebeg_c, int n0,
                                               int2* __restrict__ rowdeg,
                                               IT* __restrict__ csr, int N,
                                               int* cnt, int* sdata) {
    const int tid = threadIdx.x;
    const int NBINS = NPB * NB;          // 4096 for both configs
    const unsigned mask = (unsigned)(NPB - 1);
    int cs[SHARDS];
    for (int s = 0; s < SHARDS; ++s) cs[s] = shard_cnt[s];
    for (int i = tid; i < NBINS; i += TB) cnt[i] = 0;
    __syncthreads();
    for (int s = 0; s < SHARDS; ++s) {
        const int base = ebeg_p + s * SCAP;
        const int endv = base + cs[s];
        for (int e = base + tid; e < endv; e += TB) {
            unsigned r = part[e];
            int bin = (int)(r & mask) * NB + (int)((r >> BSHIFT) >> TSHIFT);
            atomicAdd(&cnt[bin], 1);
        }
    }
    __syncthreads();
    const int ITEMS = NBINS / TB;        // 16
    const int NPT = ITEMS / NB;          // nodes per thread (4 users / 1 artist)
    const int ib = tid * ITEMS;
    int dj[NPT], pdj[NPT], nsj[NPT];
    int local = 0;
    for (int j = 0; j < NPT; ++j) {
        int d = 0;
        for (int k = 0; k < NB; ++k) d += cnt[ib + j * NB + k];
        dj[j] = d;
        pdj[j] = (d + 3) & ~3;
        local += pdj[j];
    }
    sdata[tid] = local;
    __syncthreads();
    for (int off = 1; off < TB; off <<= 1) {
        int t = (tid >= off) ? sdata[tid - off] : 0;
        __syncthreads();
        if (tid >= off) sdata[tid] += t;
        __syncthreads();
    }
    int run = sdata[tid] - local;
    for (int j = 0; j < NPT; ++j) {
        nsj[j] = run;
        int c = run;
        for (int k = 0; k < NB; ++k) {
            int idx = ib + j * NB + k;
            int v = cnt[idx];
            cnt[idx] = c;                // per-bin fill cursor
            c += v;
        }
        int n = n0 + tid * NPT + j;
        if (n < N) rowdeg[n] = make_int2(ebeg_c + run, dj[j]);
        run += pdj[j];
    }
    __syncthreads();
    for (int s = 0; s < SHARDS; ++s) {
        const int base = ebeg_p + s * SCAP;
        const int endv = base + cs[s];
        for (int e = base + tid; e < endv; e += TB) {
            unsigned r = part[e];
            int bin = (int)(r & mask) * NB + (int)((r >> BSHIFT) >> TSHIFT);
            int pos = atomicAdd(&cnt[bin], 1);
            csr[ebeg_c + pos] = (IT)(r >> BSHIFT);
        }
    }
    // pad fill: dummy id 0 in [d, pd) of each node segment
    for (int j = 0; j < NPT; ++j)
        for (int k = dj[j]; k < pdj[j]; ++k) csr[ebeg_c + nsj[j] + k] = (IT)0;
}

__global__ __launch_bounds__(TB) void local_csr_both_kernel(const unsigned* __restrict__ part_u,
                                                            const unsigned* __restrict__ part_a,
                                                            const int* __restrict__ bcur_u,
                                                            const int* __restrict__ bcur_a,
                                                            int2* __restrict__ rowdeg_u,
                                                            int2* __restrict__ rowdeg_a,
                                                            unsigned short* __restrict__ csr_u,
                                                            int* __restrict__ csr_a,
                                                            int NU, int NA, int NBu) {
    __shared__ int cnt[4096];
    __shared__ int sdata[TB];
    const int b = blockIdx.x;
    if (b < NBu) {
        local_csr_body<1024, 4, BSHIFT_U>(part_u, bcur_u + b * SHARDS, b * CAP, b * CAPC_U,
                                          b << BSHIFT_U, rowdeg_u, csr_u, NU, cnt, sdata);
    } else {
        const int bb = b - NBu;
        local_csr_body<256, 16, BSHIFT_A>(part_a, bcur_a + bb * SHARDS, bb * CAP, bb * CAPC_A,
                                          bb << BSHIFT_A, rowdeg_a, csr_a, NA, cnt, sdata);
    }
}

// L-lane group per (node, row-slice); L=8: group owns full 128B row (artist
// gathers); L=4: two groups split the row -> 2x groups/wave -> 2x outstanding
// loads (user gathers, latency-bound). Uniform 4-wide edge loop (x4-padded
// CSR, dummy id 0) + 8-wide unroll; correction sum -= (pd-deg)*row0-slice.
template <int L, typename IT>
__global__ __launch_bounds__(TB) void gather_mean_kernel(const half8* __restrict__ src,
                                                         const IT* __restrict__ csr,
                                                         const int2* __restrict__ rowdeg,
                                                         half8* __restrict__ x_out,
                                                         f32x4* __restrict__ final_acc,
                                                         const f32x4* __restrict__ init_src,
                                                         const f32x4* __restrict__ fin_in0,
                                                         const half8* __restrict__ fin_x1,
                                                         const half8* __restrict__ fin_x2,
                                                         f32x4* __restrict__ fin_out,
                                                         int N, float scale) {
    constexpr int SPLIT = 8 / L;        // row-slices per row (1 or 2)
    const int lane = threadIdx.x & (L - 1);
    const int g = (blockIdx.x * blockDim.x + threadIdx.x) / L;
    const int ngroups = (gridDim.x * blockDim.x) / L;
    const int sub = g % SPLIT;
    const int cb = sub * L + lane;       // half8-chunk index within row, 0..7
    const int n0 = g / SPLIT;
    const int nstride = ngroups / SPLIT;
    const float8 r0 = h8_to_f8(src[cb]);   // row 0 slice (dummy target), hoisted
    for (int n = n0; n < N; n += nstride) {
        const int2 rd = rowdeg[n];
        const int beg = rd.x;
        const int dg = rd.y;
        const int pd = (dg + 3) & ~3;
        const int end = beg + pd;
        float8 a0 = 0.f, a1 = 0.f, a2 = 0.f, a3 = 0.f;
        int e = beg;
        for (; e + 8 <= end; e += 8) {
            const int s0 = (int)csr[e + 0];
            const int s1 = (int)csr[e + 1];
            const int s2 = (int)csr[e + 2];
            const int s3 = (int)csr[e + 3];
            const int s4 = (int)csr[e + 4];
            const int s5 = (int)csr[e + 5];
            const int s6 = (int)csr[e + 6];
            const int s7 = (int)csr[e + 7];
            const half8 v0 = src[s0 * 8 + cb];
            const half8 v1 = src[s1 * 8 + cb];
            const half8 v2 = src[s2 * 8 + cb];
            const half8 v3 = src[s3 * 8 + cb];
            const half8 v4 = src[s4 * 8 + cb];
            const half8 v5 = src[s5 * 8 + cb];
            const half8 v6 = src[s6 * 8 + cb];
            const half8 v7 = src[s7 * 8 + cb];
            a0 += h8_to_f8(v0);
            a1 += h8_to_f8(v1);
            a2 += h8_to_f8(v2);
            a3 += h8_to_f8(v3);
            a0 += h8_to_f8(v4);
            a1 += h8_to_f8(v5);
            a2 += h8_to_f8(v6);
            a3 += h8_to_f8(v7);
        }
        if (e < end) {   // exactly one 4-wide iteration (pd % 4 == 0)
            const int s0 = (int)csr[e + 0];
            const int s1 = (int)csr[e + 1];
            const int s2 = (int)csr[e + 2];
            const int s3 = (int)csr[e + 3];
            a0 += h8_to_f8(src[s0 * 8 + cb]);
            a1 += h8_to_f8(src[s1 * 8 + cb]);
            a2 += h8_to_f8(src[s2 * 8 + cb]);
            a3 += h8_to_f8(src[s3 * 8 + cb]);
        }
        float8 s = (a0 + a1) + (a2 + a3);
        s -= (float)(pd - dg) * r0;
        const float inv = 1.f / (float)(dg > 0 ? dg : 1);
        float8 x = s * inv;
        const int o8 = n * 8 + cb;
        if (x_out != nullptr) {
            half8 h;
            for (int k = 0; k < 8; ++k) h[k] = (_Float16)x[k];
            x_out[o8] = h;
        }
        const int fo = n * (D / 4) + cb * 2;
        if (fin_out != nullptr) {
            float8 t = h8_to_f8(ntl(&fin_x1[o8])) + h8_to_f8(ntl(&fin_x2[o8])) + x;
            f32x4 f0 = ntl(&fin_in0[fo + 0]);
            f32x4 f1 = ntl(&fin_in0[fo + 1]);
            f32x4 t0 = {t[0], t[1], t[2], t[3]};
            f32x4 t1 = {t[4], t[5], t[6], t[7]};
            nts(&fin_out[fo + 0], (f0 + t0) * scale);
            nts(&fin_out[fo + 1], (f1 + t1) * scale);
        }
        if (final_acc != nullptr) {
            f32x4 f0, f1;
            if (init_src != nullptr) {
                f0 = init_src[fo + 0] * scale;
                f1 = init_src[fo + 1] * scale;
            } else {
                f0 = final_acc[fo + 0];
                f1 = final_acc[fo + 1];
            }
            f32x4 x0 = {x[0], x[1], x[2], x[3]};
            f32x4 x1 = {x[4], x[5], x[6], x[7]};
            final_acc[fo + 0] = f0 + x0 * scale;
            final_acc[fo + 1] = f1 + x1 * scale;
        }
    }
}

extern "C" void kernel_launch(void* const* d_in, const int* in_sizes, int n_in,
                              void* d_out, int out_size, void* d_ws, size_t ws_size,
                              hipStream_t stream) {
    const float* x_users   = (const float*)d_in[0];
    const float* x_artists = (const float*)d_in[1];
    const int*   a2u       = (const int*)d_in[2];  // row0: artist(src), row1: user(dst)

    const int NU = in_sizes[0] / D;
    const int NA = in_sizes[1] / D;
    const int E  = in_sizes[2] / 2;
    const int* art = a2u;
    const int* usr = a2u + E;

    const float scale = 0.25f;   // 1/(NUM_LAYERS+1)

    const int NBu = (NU + (1 << BSHIFT_U) - 1) >> BSHIFT_U;  // 196
    const int NBa = (NA + (1 << BSHIFT_A) - 1) >> BSHIFT_A;  // 196

    // ---- workspace layout (256B aligned) ----
    char* w = (char*)d_ws;
    size_t off = 0;
    auto alloc = [&](size_t bytes) -> char* {
        char* p = w + off;
        off += (bytes + 255) & ~(size_t)255;
        return p;
    };
    int2* rowdeg_u = (int2*)alloc((size_t)NU * 8);
    int2* rowdeg_a = (int2*)alloc((size_t)NA * 8);
    int* bcur      = (int*)alloc((size_t)(NBu + NBa) * SHARDS * 4);
    int* bcur_u    = bcur;                        // [NBu][SHARDS]
    int* bcur_a    = bcur + NBu * SHARDS;         // [NBa][SHARDS]
    unsigned short* csr_u = (unsigned short*)alloc((size_t)NBu * CAPC_U * 2);
    int* csr_a     = (int*)alloc((size_t)NBa * CAPC_A * 4);
    half8* xa_in   = (half8*)alloc((size_t)NA * D * 2);   // fp16 copy of x_artists
    unsigned* part_u = (unsigned*)alloc((size_t)NBu * CAP * 4);
    unsigned* part_a = (unsigned*)alloc((size_t)NBa * CAP * 4);

    const size_t XU = (size_t)NU * D * 2;                 // 25.6 MB
    const size_t XA = (size_t)NA * D * 2;                 // 6.4 MB
    const size_t XUa = (XU + 255) & ~(size_t)255;
    const size_t XAa = (XA + 255) & ~(size_t)255;

    const bool modeA = (off + 3 * XUa) <= ws_size;

    half8* x_u1 = (half8*)alloc(XU);
    half8* x_u2 = modeA ? (half8*)alloc(XU) : x_u1;
    half8* x_u3 = modeA ? (half8*)alloc(XU) : x_u1;
    // x_a buffers overlay the (dead-after-build) part region (19.2MB >= 12.8MB)
    char* part_base = (char*)part_u;
    half8* x_a1 = (half8*)(part_base);
    half8* x_a2 = modeA ? (half8*)(part_base + XAa) : x_a1;

    float* out_u = (float*)d_out;
    float* out_a = out_u + (size_t)NU * D;

    // ---- sorted CSR build (sharded-cursor partition + fused cvt) ----
    hipMemsetAsync(bcur, 0, (size_t)(NBu + NBa) * SHARDS * 4, stream);
    const int nchunks = (E + PCHUNK - 1) / PCHUNK;
    const int nPart = 2 * nchunks;
    partition_cvt_kernel<<<nPart + 128, TB, 0, stream>>>(art, usr, E, bcur_u, bcur_a,
                                                         part_u, part_a, NBu, NBa,
                                                         (const f32x4*)x_artists, xa_in,
                                                         NA * D / 8, nPart);
    local_csr_both_kernel<<<NBu + NBa, TB, 0, stream>>>(part_u, part_a, bcur_u, bcur_a,
                                                        rowdeg_u, rowdeg_a,
                                                        csr_u, csr_a, NU, NA, NBu);

    // ---- 3 propagation layers ----
    half8* xu_buf[3] = {x_u1, x_u2, x_u3};
    half8* xa_buf[2] = {x_a1, x_a2};           // l=2 artist writes out only (Mode A)
    const half8* srcA = xa_in;
    for (int l = 0; l < 3; ++l) {
        const bool last = (l == 2);
        // users <- artists : 4-lane groups (2x MLP), uint16 csr
        gather_mean_kernel<4, unsigned short><<<4096, TB, 0, stream>>>(
            srcA, csr_u, rowdeg_u, xu_buf[l],
            modeA ? nullptr : (f32x4*)out_u,
            (!modeA && l == 0) ? (const f32x4*)x_users : nullptr,
            (modeA && last) ? (const f32x4*)x_users : nullptr,
            (modeA && last) ? x_u1 : nullptr,
            (modeA && last) ? x_u2 : nullptr,
            (modeA && last) ? (f32x4*)out_u : nullptr,
            NU, scale);
        // artists <- users : 8-lane groups, int csr
        gather_mean_kernel<8, int><<<2048, TB, 0, stream>>>(
            xu_buf[l], csr_a, rowdeg_a,
            (modeA && last) ? nullptr : (modeA ? xa_buf[l] : x_a1),
            modeA ? nullptr : (f32x4*)out_a,
            (!modeA && l == 0) ? (const f32x4*)x_artists : nullptr,
            (modeA && last) ? (const f32x4*)x_artists : nullptr,
            (modeA && last) ? x_a1 : nullptr,
            (modeA && last) ? x_a2 : nullptr,
            (modeA && last) ? (f32x4*)out_a : nullptr,
            NA, scale);
        srcA = modeA ? xa_buf[l < 2 ? l : 0] : x_a1;
    }
}